// Round 4
// baseline (511.290 us; speedup 1.0000x reference)
//
#include <hip/hip_runtime.h>

#define N_NODES   50000
#define N_EDGES   1600000
#define FDIM_IN   128
#define HDIM      160
#define N_GRAPHS  512
#define BN_EPS    1e-5f
#define NBKT_MAX  128           // coarse buckets of 512 nodes (N<=65536)

typedef short  frag8 __attribute__((ext_vector_type(8)));   // 8 x bf16
typedef float  facc4 __attribute__((ext_vector_type(4)));   // 4 x f32
typedef unsigned int u32x4 __attribute__((ext_vector_type(4)));  // for nontemporal 16B store

// ---------------- bf16 helpers ----------------

__device__ __forceinline__ unsigned short f2bf(float f) {
    unsigned int u = __float_as_uint(f);
    return (unsigned short)((u + 0x7FFFu + ((u >> 16) & 1u)) >> 16);
}

__device__ __forceinline__ unsigned int pack2(float lo, float hi) {
    return (unsigned int)f2bf(lo) | ((unsigned int)f2bf(hi) << 16);
}

__device__ __forceinline__ void addpk(float* acc, uint4 r) {
    acc[0] += __uint_as_float(r.x << 16);
    acc[1] += __uint_as_float(r.x & 0xFFFF0000u);
    acc[2] += __uint_as_float(r.y << 16);
    acc[3] += __uint_as_float(r.y & 0xFFFF0000u);
    acc[4] += __uint_as_float(r.z << 16);
    acc[5] += __uint_as_float(r.z & 0xFFFF0000u);
    acc[6] += __uint_as_float(r.w << 16);
    acc[7] += __uint_as_float(r.w & 0xFFFF0000u);
}

// ---------------- two-level counting sort by dst ----------------

__global__ __launch_bounds__(256) void coarse_hist_kernel(const int* __restrict__ dst,
                                                          int* __restrict__ cg, int E) {
    __shared__ int h[NBKT_MAX];
    int tid = threadIdx.x;
    if (tid < NBKT_MAX) h[tid] = 0;
    __syncthreads();
    for (int e = blockIdx.x * 256 + tid; e < E; e += gridDim.x * 256)
        atomicAdd(&h[dst[e] >> 9], 1);
    __syncthreads();
    if (tid < NBKT_MAX && h[tid]) atomicAdd(&cg[tid], h[tid]);
}

__global__ __launch_bounds__(128) void coarse_scan_kernel(const int* __restrict__ cg,
                                                          int* __restrict__ bucket_base,
                                                          int* __restrict__ bucket_cursor) {
    __shared__ int h[NBKT_MAX];
    int t = threadIdx.x;
    h[t] = cg[t];
    __syncthreads();
    if (t == 0) {
        int run = 0;
        for (int i = 0; i < NBKT_MAX; ++i) { int c = h[i]; h[i] = run; run += c; }
    }
    __syncthreads();
    bucket_base[t] = h[t];
    bucket_cursor[t] = h[t];
    if (t == 0) bucket_base[NBKT_MAX] = h[NBKT_MAX - 1] + cg[NBKT_MAX - 1];
}

// level 1: partition packed (src<<9 | dst&511) into coarse-bucket-contiguous regions
__global__ __launch_bounds__(256) void part_kernel(const int* __restrict__ src,
                                                   const int* __restrict__ dst,
                                                   int* __restrict__ bucket_cursor,
                                                   unsigned int* __restrict__ pairs, int E) {
    __shared__ int bcnt[NBKT_MAX], bbase[NBKT_MAX], lc[NBKT_MAX];
    int tid = threadIdx.x;
    int per = (E + gridDim.x - 1) / gridDim.x;
    int beg = blockIdx.x * per;
    int end = min(beg + per, E);
    if (tid < NBKT_MAX) { bcnt[tid] = 0; lc[tid] = 0; }
    __syncthreads();
    for (int e = beg + tid; e < end; e += 256)
        atomicAdd(&bcnt[dst[e] >> 9], 1);
    __syncthreads();
    if (tid < NBKT_MAX)
        bbase[tid] = bcnt[tid] ? atomicAdd(&bucket_cursor[tid], bcnt[tid]) : 0;
    __syncthreads();
    for (int e = beg + tid; e < end; e += 256) {
        int d = dst[e];
        int b = d >> 9;
        int pos = bbase[b] + atomicAdd(&lc[b], 1);
        pairs[pos] = ((unsigned int)src[e] << 9) | (unsigned int)(d & 511);
    }
}

// level 2: per-bucket exact CSR build + local scatter (dest window L2-resident)
__global__ __launch_bounds__(1024) void bucket_csr_kernel(const unsigned int* __restrict__ pairs,
                                                          const int* __restrict__ bucket_base,
                                                          int* __restrict__ row_off,
                                                          float* __restrict__ inv,
                                                          int* __restrict__ ssrc, int n) {
    __shared__ int h[512];
    __shared__ int ws[8];
    int tid = threadIdx.x;
    int b = blockIdx.x;
    int node0 = b << 9;
    int beg = bucket_base[b], end = bucket_base[b + 1];
    if (tid < 512) h[tid] = 0;
    __syncthreads();
    for (int j = beg + tid; j < end; j += 1024)
        atomicAdd(&h[pairs[j] & 511], 1);
    __syncthreads();
    int cntv = (tid < 512) ? h[tid] : 0;
    __syncthreads();
    int lane = tid & 63, wid = tid >> 6;
    int incl = cntv;
    #pragma unroll
    for (int off = 1; off < 64; off <<= 1) {
        int u = __shfl_up(incl, off);
        if (lane >= off) incl += u;
    }
    if (tid < 512 && lane == 63) ws[wid] = incl;
    __syncthreads();
    if (tid == 0) {
        int r = 0;
        #pragma unroll
        for (int i = 0; i < 8; ++i) { int t = ws[i]; ws[i] = r; r += t; }
    }
    __syncthreads();
    int excl = (tid < 512) ? (ws[wid] + incl - cntv) : 0;
    if (tid < 512) {
        int node = node0 + tid;
        if (node < n) {
            row_off[node] = beg + excl;
            inv[node] = rsqrtf((float)(cntv + 1));   // +1 = self loop
        }
        h[tid] = excl;
    }
    if (tid == 0 && (node0 + 512) >= n) row_off[n] = end;
    __syncthreads();
    for (int j = beg + tid; j < end; j += 1024) {
        unsigned int p = pairs[j];
        int pos = beg + atomicAdd(&h[p & 511], 1);
        ssrc[pos] = (int)(p >> 9);
    }
}

// ---------------- BN fold (3 layers in one launch) ----------------

struct PrepArgs {
    const float *b, *g, *be, *m, *v;
    float *sc, *sh;
};

__global__ void prep3_kernel(PrepArgs a0, PrepArgs a1, PrepArgs a2) {
    PrepArgs a = (blockIdx.x == 0) ? a0 : (blockIdx.x == 1) ? a1 : a2;
    int t = threadIdx.x;
    if (t < HDIM) {
        float s = a.g[t] * rsqrtf(a.v[t] + BN_EPS);
        a.sc[t] = s;
        a.sh[t] = (a.b[t] - a.m[t]) * s + a.be[t];
    }
}

// ---------------- weight pack: W fp32 [K x 160] -> bf16 MFMA B-fragment order ----------------
// all three weights in one launch

__global__ __launch_bounds__(256) void pack_w3_kernel(const float* __restrict__ W1,
                                                      const float* __restrict__ W2,
                                                      const float* __restrict__ W3,
                                                      unsigned short* __restrict__ o1,
                                                      unsigned short* __restrict__ o2,
                                                      unsigned short* __restrict__ o3) {
    int tid = blockIdx.x * 256 + threadIdx.x;
    const float* W;
    unsigned short* o;
    int i;
    if (tid < 128 * 160)             { W = W1; o = o1; i = tid; }
    else if (tid < 128 * 160 + 160 * 160) { W = W2; o = o2; i = tid - 128 * 160; }
    else if (tid < 128 * 160 + 2 * 160 * 160) { W = W3; o = o3; i = tid - (128 * 160 + 160 * 160); }
    else return;
    int j = i & 7;
    int l = (i >> 3) & 63;
    int u = (i >> 9) % 10;
    int t = i / 5120;
    int k = t * 32 + (l >> 4) * 8 + j;
    int nn = u * 16 + (l & 15);
    o[i] = f2bf(W[k * 160 + nn]);
}

// ---------------- pre-scale + pack: out_bf16 = x * inv[node], sliced [4][n][32] ----------------

__global__ __launch_bounds__(256) void scale_bf16_kernel(const float* __restrict__ x,
                                                         const float* __restrict__ inv,
                                                         unsigned short* __restrict__ out,
                                                         int n) {
    int i = blockIdx.x * 256 + threadIdx.x;      // float4 index over n*32
    if (i < n * 32) {
        int node = i >> 5;
        int q4 = i & 31;                          // which float4 within row (4 ch each)
        float w = inv[node];
        float4 v = ((const float4*)x)[i];
        ushort4 o;
        o.x = f2bf(v.x * w); o.y = f2bf(v.y * w);
        o.z = f2bf(v.z * w); o.w = f2bf(v.w * w);
        int sl = q4 >> 3;                         // slice = c0/32, c0 = q4*4
        int cc = (q4 & 7) * 4;                    // channel within slice
        size_t sstr = (size_t)n * 32;
        *(ushort4*)(out + (size_t)sl * sstr + (size_t)node * 32 + cc) = o;
    }
}

// ---------------- sliced gather aggregation (bf16 in, bf16 out) ----------------
// Feature buffers are slice-major [S][n][32ch]; one row-slice = 64B = 1 cacheline.
// One 3.2MB slice fits per-XCD L2 -> gather working set is L2-resident per pass.
// Grid = bpS * S; slice is the slow blockIdx dim so concurrently-resident blocks
// share one slice. Wave: 4 nodes (j) x 4 edge-groups (gg) x 4 lanes (cl, 16B).
// ssrc re-reads and output stores are non-temporal to not evict the slice.

__global__ __launch_bounds__(256) void agg_slice_kernel(const unsigned short* __restrict__ in_s,
                                                        const float* __restrict__ inv,
                                                        const int* __restrict__ row_off,
                                                        const int* __restrict__ ssrc,
                                                        unsigned short* __restrict__ out,
                                                        int n, int bpS) {
    int s  = blockIdx.x / bpS;
    int nb = blockIdx.x - s * bpS;
    int wave = threadIdx.x >> 6;
    int lane = threadIdx.x & 63;
    int j  = lane >> 4;          // node sub-index 0..3
    int gg = (lane >> 2) & 3;    // edge group within node 0..3
    int cl = lane & 3;           // 16B chunk within 64B row-slice
    int node = nb * 16 + wave * 4 + j;
    if (node >= n) return;

    size_t sstr = (size_t)n * 32;                 // ushorts per slice
    const char* base = (const char*)(in_s + (size_t)s * sstr);
    int beg = row_off[node], end = row_off[node + 1];
    int lb = cl * 16;

    float acc[8];
    #pragma unroll
    for (int i = 0; i < 8; ++i) acc[i] = 0.f;

    if (gg == 0) {   // self-loop term
        uint4 r = *(const uint4*)(base + (size_t)node * 64 + lb);
        addpk(acc, r);
    }

    int e = beg + gg;
    for (; e + 4 < end; e += 8) {
        int s0 = __builtin_nontemporal_load(&ssrc[e]);
        int s1 = __builtin_nontemporal_load(&ssrc[e + 4]);
        uint4 r0 = *(const uint4*)(base + (size_t)s0 * 64 + lb);
        uint4 r1 = *(const uint4*)(base + (size_t)s1 * 64 + lb);
        addpk(acc, r0);
        addpk(acc, r1);
    }
    if (e < end) {
        int s0 = __builtin_nontemporal_load(&ssrc[e]);
        uint4 r = *(const uint4*)(base + (size_t)s0 * 64 + lb);
        addpk(acc, r);
    }

    // reduce across the 4 edge groups of this node (lane bits 2,3)
    #pragma unroll
    for (int i = 0; i < 8; ++i) {
        acc[i] += __shfl_xor(acc[i], 4);
        acc[i] += __shfl_xor(acc[i], 8);
    }

    if (gg == 0) {
        float wi = inv[node];
        u32x4 o;
        o.x = pack2(acc[0] * wi, acc[1] * wi);
        o.y = pack2(acc[2] * wi, acc[3] * wi);
        o.z = pack2(acc[4] * wi, acc[5] * wi);
        o.w = pack2(acc[6] * wi, acc[7] * wi);
        __builtin_nontemporal_store(o, (u32x4*)((char*)(out + (size_t)s * sstr) + (size_t)node * 64 + lb));
    }
}

// ---------------- MFMA GEMM: relu((A[n x K]bf16 @ B[K x 160]bf16) * sc + sh) ----------------
// A is slice-major [KT][n][32]; OUTMODE=1 writes sliced bf16 [5][n][32], OUTMODE=0 dense fp32.

template <int K, int OUTMODE>
__global__ __launch_bounds__(256) void mfma_gemm_kernel(const unsigned short* __restrict__ A,
                                                        const unsigned short* __restrict__ Bp,
                                                        const float* __restrict__ sc,
                                                        const float* __restrict__ sh,
                                                        const float* __restrict__ inv,
                                                        float* __restrict__ CoutF,
                                                        unsigned short* __restrict__ CoutB,
                                                        int n) {
    constexpr int KT = K / 32;
    int tid = threadIdx.x;
    int wave = tid >> 6, lane = tid & 63;
    int row0 = blockIdx.x * 64 + wave * 16;
    int m = lane & 15, q = lane >> 4;

    int arow = row0 + m;
    int arowc = (arow < n) ? arow : (n - 1);
    size_t sstr = (size_t)n * 32;
    const frag8* Bbase = (const frag8*)Bp;                        // frag idx = (t*10+u)*64 + lane

    facc4 acc[10];
    #pragma unroll
    for (int u = 0; u < 10; ++u) acc[u] = (facc4){0.f, 0.f, 0.f, 0.f};

    #pragma unroll
    for (int t = 0; t < KT; ++t) {
        frag8 af = *(const frag8*)(A + (size_t)t * sstr + (size_t)arowc * 32 + q * 8);
        #pragma unroll
        for (int u = 0; u < 10; ++u) {
            frag8 bf = Bbase[(t * 10 + u) * 64 + lane];
            acc[u] = __builtin_amdgcn_mfma_f32_16x16x32_bf16(af, bf, acc[u], 0, 0, 0);
        }
    }

    // D layout: col = lane&15 (within tile), row = q*4 + reg
    #pragma unroll
    for (int u = 0; u < 10; ++u) {
        int c = u * 16 + m;
        float scv = sc[c], shv = sh[c];
        #pragma unroll
        for (int r = 0; r < 4; ++r) {
            int rr = row0 + q * 4 + r;
            if (rr < n) {
                float v = fmaxf(acc[u][r] * scv + shv, 0.f);
                if (OUTMODE == 1) {
                    CoutB[(size_t)(c >> 5) * sstr + (size_t)rr * 32 + (c & 31)] = f2bf(v * inv[rr]);
                } else {
                    CoutF[(size_t)rr * 160 + c] = v;
                }
            }
        }
    }
}

// ---------------- mean pool (sorted batch) + MLP head ----------------

__global__ __launch_bounds__(256) void pool_head_kernel(const float* __restrict__ h,
                                                        const int* __restrict__ batch,
                                                        const float* __restrict__ Wc1,
                                                        const float* __restrict__ bc1,
                                                        const float* __restrict__ Wc2,
                                                        const float* __restrict__ bc2,
                                                        float* __restrict__ out, int n) {
    __shared__ float pooled[160];
    __shared__ float z[80];
    __shared__ int range[2];
    int g = blockIdx.x;
    int t = threadIdx.x;
    if (t < 2) {
        int target = g + t;
        int lo = 0, hi = n;
        while (lo < hi) {
            int mid = (lo + hi) >> 1;
            if (batch[mid] < target) lo = mid + 1; else hi = mid;
        }
        range[t] = lo;
    }
    __syncthreads();
    int lo = range[0], hi = range[1];
    if (t < 160) {
        float s = 0.f;
        for (int r = lo; r < hi; ++r) s += h[(size_t)r * 160 + t];
        pooled[t] = s / fmaxf((float)(hi - lo), 1.f);
    }
    __syncthreads();
    if (t < 80) {
        float s = bc1[t];
        for (int k = 0; k < 160; ++k) s += pooled[k] * Wc1[k * 80 + t];
        z[t] = fmaxf(s, 0.f);
    }
    __syncthreads();
    if (t < 2) {
        float s = bc2[t];
        for (int k = 0; k < 80; ++k) s += z[k] * Wc2[k * 2 + t];
        out[g * 2 + t] = s;
    }
}

// ---------------- launch ----------------

static inline size_t align256(size_t x) { return (x + 255) & ~(size_t)255; }

extern "C" void kernel_launch(void* const* d_in, const int* in_sizes, int n_in,
                              void* d_out, int out_size, void* d_ws, size_t ws_size,
                              hipStream_t stream) {
    const float* x   = (const float*)d_in[0];
    const int* ei    = (const int*)d_in[1];
    const int* batch = (const int*)d_in[2];
    const float* W1  = (const float*)d_in[3];
    const float* b1  = (const float*)d_in[4];
    const float* W2  = (const float*)d_in[5];
    const float* b2  = (const float*)d_in[6];
    const float* W3  = (const float*)d_in[7];
    const float* b3  = (const float*)d_in[8];
    const float* g1  = (const float*)d_in[9];
    const float* be1 = (const float*)d_in[10];
    const float* m1  = (const float*)d_in[11];
    const float* v1  = (const float*)d_in[12];
    const float* g2  = (const float*)d_in[13];
    const float* be2 = (const float*)d_in[14];
    const float* m2  = (const float*)d_in[15];
    const float* v2  = (const float*)d_in[16];
    const float* g3  = (const float*)d_in[17];
    const float* be3 = (const float*)d_in[18];
    const float* m3  = (const float*)d_in[19];
    const float* v3  = (const float*)d_in[20];
    const float* Wc1 = (const float*)d_in[21];
    const float* bc1 = (const float*)d_in[22];
    const float* Wc2 = (const float*)d_in[23];
    const float* bc2 = (const float*)d_in[24];
    float* out = (float*)d_out;

    const int N = in_sizes[2];          // 50000
    const int E = in_sizes[1] / 2;      // 1600000
    const int* src = ei;
    const int* dst = ei + E;

    char* w = (char*)d_ws;
    int*   row_off = (int*)w;             w += align256((size_t)(N + 1) * 4);
    float* inv     = (float*)w;           w += align256((size_t)N * 4);
    int*   ssrc    = (int*)w;             w += align256((size_t)E * 4);
    unsigned int* pairs = (unsigned int*)w; w += align256((size_t)E * 4);
    int*   cg      = (int*)w;             w += align256((size_t)NBKT_MAX * 4);
    int*   bucket_base   = (int*)w;       w += align256((size_t)(NBKT_MAX + 1) * 4);
    int*   bucket_cursor = (int*)w;       w += align256((size_t)NBKT_MAX * 4);
    float* scsh    = (float*)w;           w += align256((size_t)6 * HDIM * 4);
    unsigned short* W1p = (unsigned short*)w;  w += align256((size_t)FDIM_IN * HDIM * 2);
    unsigned short* W2p = (unsigned short*)w;  w += align256((size_t)HDIM * HDIM * 2);
    unsigned short* W3p = (unsigned short*)w;  w += align256((size_t)HDIM * HDIM * 2);
    unsigned short* bufA_bf = (unsigned short*)w;  w += align256((size_t)N * HDIM * 2);
    char* regionR = w;                    // reused region
    unsigned short* xs_bf = (unsigned short*)regionR;                           // 4 slices x N*32
    unsigned short* hs_bf = (unsigned short*)(regionR + align256((size_t)N * FDIM_IN * 2)); // 5 slices x N*32
    float* bufB = (float*)regionR;        // final h3 fp32 (aliases xs/hs, both dead by then)
    float* sc1 = scsh, *sh1 = scsh + 160, *sc2 = scsh + 320, *sh2 = scsh + 480,
         * sc3 = scsh + 640, *sh3 = scsh + 800;

    (void)hipMemsetAsync(cg, 0, (size_t)NBKT_MAX * 4, stream);

    // two-level counting sort by dst -> row_off, ssrc, inv
    coarse_hist_kernel<<<256, 256, 0, stream>>>(dst, cg, E);
    coarse_scan_kernel<<<1, 128, 0, stream>>>(cg, bucket_base, bucket_cursor);
    part_kernel<<<256, 256, 0, stream>>>(src, dst, bucket_cursor, pairs, E);
    int nbkt = (N + 511) >> 9;
    bucket_csr_kernel<<<nbkt, 1024, 0, stream>>>(pairs, bucket_base, row_off, inv, ssrc, N);

    PrepArgs pa0 = {b1, g1, be1, m1, v1, sc1, sh1};
    PrepArgs pa1 = {b2, g2, be2, m2, v2, sc2, sh2};
    PrepArgs pa2 = {b3, g3, be3, m3, v3, sc3, sh3};
    prep3_kernel<<<3, 256, 0, stream>>>(pa0, pa1, pa2);
    pack_w3_kernel<<<(128 * 160 + 2 * 160 * 160 + 255) / 256, 256, 0, stream>>>(W1, W2, W3, W1p, W2p, W3p);

    int bpS = (N + 15) / 16;            // blocks per slice (16 nodes per block)
    int gGemm = (N + 63) / 64;

    // layer 1: xs = bf16(x*inv) sliced[4]; agg (4 slices); GEMM(K=128)+BN+ReLU -> sliced[5] bf16(h*inv)
    scale_bf16_kernel<<<(N * 32 + 255) / 256, 256, 0, stream>>>(x, inv, xs_bf, N);
    agg_slice_kernel<<<bpS * 4, 256, 0, stream>>>(xs_bf, inv, row_off, ssrc, bufA_bf, N, bpS);
    mfma_gemm_kernel<128, 1><<<gGemm, 256, 0, stream>>>(bufA_bf, W1p, sc1, sh1, inv, nullptr, hs_bf, N);
    // layer 2 (5 slices)
    agg_slice_kernel<<<bpS * 5, 256, 0, stream>>>(hs_bf, inv, row_off, ssrc, bufA_bf, N, bpS);
    mfma_gemm_kernel<160, 1><<<gGemm, 256, 0, stream>>>(bufA_bf, W2p, sc2, sh2, inv, nullptr, hs_bf, N);
    // layer 3: fp32 unscaled h3 for pooling (bufB aliases dead xs/hs region)
    agg_slice_kernel<<<bpS * 5, 256, 0, stream>>>(hs_bf, inv, row_off, ssrc, bufA_bf, N, bpS);
    mfma_gemm_kernel<160, 0><<<gGemm, 256, 0, stream>>>(bufA_bf, W3p, sc3, sh3, inv, bufB, nullptr, N);

    pool_head_kernel<<<N_GRAPHS, 256, 0, stream>>>(bufB, batch, Wc1, bc1, Wc2, bc2, out, N);
}

// Round 5
// 466.446 us; speedup vs baseline: 1.0961x; 1.0961x over previous
//
#include <hip/hip_runtime.h>

#define N_NODES   50000
#define N_EDGES   1600000
#define FDIM_IN   128
#define HDIM      160
#define N_GRAPHS  512
#define BN_EPS    1e-5f
#define NBKT_MAX  128           // coarse buckets of 512 nodes (N<=65536)
#define HIST_BLOCKS 256

typedef short  frag8 __attribute__((ext_vector_type(8)));   // 8 x bf16
typedef float  facc4 __attribute__((ext_vector_type(4)));   // 4 x f32

// ---------------- bf16 helpers ----------------

__device__ __forceinline__ unsigned short f2bf(float f) {
    unsigned int u = __float_as_uint(f);
    return (unsigned short)((u + 0x7FFFu + ((u >> 16) & 1u)) >> 16);
}

__device__ __forceinline__ unsigned int pack2(float lo, float hi) {
    return (unsigned int)f2bf(lo) | ((unsigned int)f2bf(hi) << 16);
}

__device__ __forceinline__ void addpk(float* acc, uint4 r) {
    acc[0] += __uint_as_float(r.x << 16);
    acc[1] += __uint_as_float(r.x & 0xFFFF0000u);
    acc[2] += __uint_as_float(r.y << 16);
    acc[3] += __uint_as_float(r.y & 0xFFFF0000u);
    acc[4] += __uint_as_float(r.z << 16);
    acc[5] += __uint_as_float(r.z & 0xFFFF0000u);
    acc[6] += __uint_as_float(r.w << 16);
    acc[7] += __uint_as_float(r.w & 0xFFFF0000u);
}

// ---------------- two-level counting sort by dst ----------------
// v2: per-block histogram rows cg[block][bucket] -> no memset, no global atomics.

__global__ __launch_bounds__(256) void coarse_hist_kernel(const int* __restrict__ dst,
                                                          int* __restrict__ cg, int E) {
    __shared__ int h[NBKT_MAX];
    int tid = threadIdx.x;
    if (tid < NBKT_MAX) h[tid] = 0;
    __syncthreads();
    for (int e = blockIdx.x * 256 + tid; e < E; e += gridDim.x * 256)
        atomicAdd(&h[dst[e] >> 9], 1);
    __syncthreads();
    if (tid < NBKT_MAX) cg[blockIdx.x * NBKT_MAX + tid] = h[tid];
}

// ---------------- merged setup: scan (block 0) + BN fold (blocks 1-3) + weight pack ----------------

struct PrepArgs {
    const float *b, *g, *be, *m, *v;
    float *sc, *sh;
};

__global__ __launch_bounds__(256) void setup_kernel(const int* __restrict__ cg,
                                                    int* __restrict__ bucket_base,
                                                    int* __restrict__ bucket_cursor,
                                                    PrepArgs a0, PrepArgs a1, PrepArgs a2,
                                                    const float* __restrict__ W1,
                                                    const float* __restrict__ W2,
                                                    const float* __restrict__ W3,
                                                    unsigned short* __restrict__ o1,
                                                    unsigned short* __restrict__ o2,
                                                    unsigned short* __restrict__ o3) {
    int bid = blockIdx.x;
    int t = threadIdx.x;
    if (bid == 0) {
        // column-sum the per-block histograms, then exclusive scan
        __shared__ int h[NBKT_MAX];
        __shared__ int total;
        if (t < NBKT_MAX) {
            int s = 0;
            for (int b = 0; b < HIST_BLOCKS; ++b) s += cg[b * NBKT_MAX + t];
            h[t] = s;
        }
        __syncthreads();
        if (t == 0) {
            int run = 0;
            for (int i = 0; i < NBKT_MAX; ++i) { int c = h[i]; h[i] = run; run += c; }
            total = run;
        }
        __syncthreads();
        if (t < NBKT_MAX) {
            bucket_base[t] = h[t];
            bucket_cursor[t] = h[t];
        }
        if (t == 0) bucket_base[NBKT_MAX] = total;
    } else if (bid <= 3) {
        PrepArgs a = (bid == 1) ? a0 : (bid == 2) ? a1 : a2;
        if (t < HDIM) {
            float s = a.g[t] * rsqrtf(a.v[t] + BN_EPS);
            a.sc[t] = s;
            a.sh[t] = (a.b[t] - a.m[t]) * s + a.be[t];
        }
    } else {
        int i = (bid - 4) * 256 + t;     // packed index over all three weights
        const float* W;
        unsigned short* o;
        if (i < 128 * 160)                 { W = W1; o = o1; }
        else if (i < 128 * 160 + 160 * 160) { W = W2; o = o2; i -= 128 * 160; }
        else if (i < 128 * 160 + 2 * 160 * 160) { W = W3; o = o3; i -= 128 * 160 + 160 * 160; }
        else return;
        int j = i & 7;
        int l = (i >> 3) & 63;
        int u = (i >> 9) % 10;
        int tt = i / 5120;
        int k = tt * 32 + (l >> 4) * 8 + j;
        int nn = u * 16 + (l & 15);
        o[i] = f2bf(W[k * 160 + nn]);
    }
}

// level 1: partition packed (src<<9 | dst&511) into coarse-bucket-contiguous regions
__global__ __launch_bounds__(256) void part_kernel(const int* __restrict__ src,
                                                   const int* __restrict__ dst,
                                                   int* __restrict__ bucket_cursor,
                                                   unsigned int* __restrict__ pairs, int E) {
    __shared__ int bcnt[NBKT_MAX], bbase[NBKT_MAX], lc[NBKT_MAX];
    int tid = threadIdx.x;
    int per = (E + gridDim.x - 1) / gridDim.x;
    int beg = blockIdx.x * per;
    int end = min(beg + per, E);
    if (tid < NBKT_MAX) { bcnt[tid] = 0; lc[tid] = 0; }
    __syncthreads();
    for (int e = beg + tid; e < end; e += 256)
        atomicAdd(&bcnt[dst[e] >> 9], 1);
    __syncthreads();
    if (tid < NBKT_MAX)
        bbase[tid] = bcnt[tid] ? atomicAdd(&bucket_cursor[tid], bcnt[tid]) : 0;
    __syncthreads();
    for (int e = beg + tid; e < end; e += 256) {
        int d = dst[e];
        int b = d >> 9;
        int pos = bbase[b] + atomicAdd(&lc[b], 1);
        pairs[pos] = ((unsigned int)src[e] << 9) | (unsigned int)(d & 511);
    }
}

// level 2: per-bucket exact CSR build + local scatter + fused x*inv bf16 pre-scale
__global__ __launch_bounds__(1024) void bucket_csr_kernel(const unsigned int* __restrict__ pairs,
                                                          const int* __restrict__ bucket_base,
                                                          int* __restrict__ row_off,
                                                          float* __restrict__ inv,
                                                          int* __restrict__ ssrc,
                                                          const float* __restrict__ x,
                                                          unsigned short* __restrict__ xs,
                                                          int n) {
    __shared__ int h[512];
    __shared__ int ws[8];
    __shared__ float sinv[512];
    int tid = threadIdx.x;
    int b = blockIdx.x;
    int node0 = b << 9;
    int beg = bucket_base[b], end = bucket_base[b + 1];
    if (tid < 512) h[tid] = 0;
    __syncthreads();
    for (int j = beg + tid; j < end; j += 1024)
        atomicAdd(&h[pairs[j] & 511], 1);
    __syncthreads();
    int cntv = (tid < 512) ? h[tid] : 0;
    __syncthreads();
    int lane = tid & 63, wid = tid >> 6;
    int incl = cntv;
    #pragma unroll
    for (int off = 1; off < 64; off <<= 1) {
        int u = __shfl_up(incl, off);
        if (lane >= off) incl += u;
    }
    if (tid < 512 && lane == 63) ws[wid] = incl;
    __syncthreads();
    if (tid == 0) {
        int r = 0;
        #pragma unroll
        for (int i = 0; i < 8; ++i) { int t = ws[i]; ws[i] = r; r += t; }
    }
    __syncthreads();
    int excl = (tid < 512) ? (ws[wid] + incl - cntv) : 0;
    if (tid < 512) {
        float iv = rsqrtf((float)(cntv + 1));    // +1 = self loop
        int node = node0 + tid;
        if (node < n) {
            row_off[node] = beg + excl;
            inv[node] = iv;
        }
        sinv[tid] = iv;
        h[tid] = excl;
    }
    if (tid == 0 && (node0 + 512) >= n) row_off[n] = end;
    __syncthreads();
    for (int j = beg + tid; j < end; j += 1024) {
        unsigned int p = pairs[j];
        int pos = beg + atomicAdd(&h[p & 511], 1);
        ssrc[pos] = (int)(p >> 9);
    }
    // fused pre-scale: xs[node] = bf16(x[node] * inv[node]) for this bucket's nodes
    for (int idx = tid; idx < 512 * 32; idx += 1024) {
        int nd = node0 + (idx >> 5);
        if (nd < n) {
            float w = sinv[idx >> 5];
            float4 v = ((const float4*)x)[(size_t)nd * 32 + (idx & 31)];
            ushort4 o;
            o.x = f2bf(v.x * w); o.y = f2bf(v.y * w);
            o.z = f2bf(v.z * w); o.w = f2bf(v.w * w);
            ((ushort4*)xs)[(size_t)nd * 32 + (idx & 31)] = o;
        }
    }
}

// ---------------- grouped-gather aggregation (bf16 in, bf16 out) ----------------
// in_s[bf16] = h*inv (per-row). out[i] = bf16( inv[i] * (sum_nbr in_s[s] + in_s[i]) )
// Wave per node; wave split into G groups of LPR lanes; each group gathers a
// different edge's row with uint4 (16B) loads. C=160: G=3x20; C=128: G=4x16.
// 2-deep ladder (R1 showed deeper ILP is neutral: vector-memory path-bound).

template <int C>
__global__ __launch_bounds__(256) void agg_grp_kernel(const unsigned short* __restrict__ in_s,
                                                      const float* __restrict__ inv,
                                                      const int* __restrict__ row_off,
                                                      const int* __restrict__ ssrc,
                                                      unsigned short* __restrict__ out, int n) {
    constexpr int LPR = C / 8;          // lanes per row (uint4 = 8 ch)
    constexpr int G   = 64 / LPR;       // concurrent edges per wave
    constexpr int RB  = C * 2;          // row bytes
    int wave = threadIdx.x >> 6;
    int lane = threadIdx.x & 63;
    int node = blockIdx.x * 4 + wave;
    if (node >= n) return;
    int g  = lane / LPR;
    int cl = lane - g * LPR;
    bool act = g < G;
    int beg = row_off[node], end = row_off[node + 1];
    const char* base = (const char*)in_s;
    int lb = cl * 16;

    float acc[8];
    #pragma unroll
    for (int i = 0; i < 8; ++i) acc[i] = 0.f;

    if (g == 0) {   // self-loop term
        uint4 r = *(const uint4*)(base + (size_t)node * RB + lb);
        addpk(acc, r);
    }

    int e = act ? beg + g : end;
    for (; e + G < end; e += 2 * G) {
        int s0 = ssrc[e], s1 = ssrc[e + G];
        uint4 r0 = *(const uint4*)(base + (size_t)s0 * RB + lb);
        uint4 r1 = *(const uint4*)(base + (size_t)s1 * RB + lb);
        addpk(acc, r0);
        addpk(acc, r1);
    }
    if (e < end) {
        uint4 r = *(const uint4*)(base + (size_t)ssrc[e] * RB + lb);
        addpk(acc, r);
    }

    // cross-group combine
    if (G == 4) {
        #pragma unroll
        for (int i = 0; i < 8; ++i) acc[i] += __shfl(acc[i], lane + 32);
        #pragma unroll
        for (int i = 0; i < 8; ++i) acc[i] += __shfl(acc[i], lane + 16);
    } else {
        #pragma unroll
        for (int i = 0; i < 8; ++i) {
            float a = __shfl(acc[i], lane + 20);
            float b = __shfl(acc[i], lane + 40);
            acc[i] += a + b;
        }
    }

    if (lane < LPR) {
        float wi = inv[node];
        uint4 o;
        o.x = pack2(acc[0] * wi, acc[1] * wi);
        o.y = pack2(acc[2] * wi, acc[3] * wi);
        o.z = pack2(acc[4] * wi, acc[5] * wi);
        o.w = pack2(acc[6] * wi, acc[7] * wi);
        *(uint4*)((char*)out + (size_t)node * RB + lb) = o;
    }
}

// ---------------- MFMA GEMM: relu((A[n x K]bf16 @ B[K x 160]bf16) * sc + sh) ----------------

template <int K, int OUTMODE>
__global__ __launch_bounds__(256) void mfma_gemm_kernel(const unsigned short* __restrict__ A,
                                                        const unsigned short* __restrict__ Bp,
                                                        const float* __restrict__ sc,
                                                        const float* __restrict__ sh,
                                                        const float* __restrict__ inv,
                                                        float* __restrict__ CoutF,
                                                        unsigned short* __restrict__ CoutB,
                                                        int n) {
    constexpr int KT = K / 32;
    int tid = threadIdx.x;
    int wave = tid >> 6, lane = tid & 63;
    int row0 = blockIdx.x * 64 + wave * 16;
    int m = lane & 15, q = lane >> 4;

    int arow = row0 + m;
    int arowc = (arow < n) ? arow : (n - 1);
    const frag8* Abase = (const frag8*)(A + (size_t)arowc * K);   // frag idx = t*4 + q
    const frag8* Bbase = (const frag8*)Bp;                        // frag idx = (t*10+u)*64 + lane

    facc4 acc[10];
    #pragma unroll
    for (int u = 0; u < 10; ++u) acc[u] = (facc4){0.f, 0.f, 0.f, 0.f};

    #pragma unroll
    for (int t = 0; t < KT; ++t) {
        frag8 af = Abase[t * 4 + q];
        #pragma unroll
        for (int u = 0; u < 10; ++u) {
            frag8 bf = Bbase[(t * 10 + u) * 64 + lane];
            acc[u] = __builtin_amdgcn_mfma_f32_16x16x32_bf16(af, bf, acc[u], 0, 0, 0);
        }
    }

    // D layout: col = lane&15 (within tile), row = q*4 + reg
    #pragma unroll
    for (int u = 0; u < 10; ++u) {
        int c = u * 16 + m;
        float scv = sc[c], shv = sh[c];
        #pragma unroll
        for (int r = 0; r < 4; ++r) {
            int rr = row0 + q * 4 + r;
            if (rr < n) {
                float v = fmaxf(acc[u][r] * scv + shv, 0.f);
                if (OUTMODE == 1) {
                    CoutB[(size_t)rr * 160 + c] = f2bf(v * inv[rr]);
                } else {
                    CoutF[(size_t)rr * 160 + c] = v;
                }
            }
        }
    }
}

// ---------------- mean pool (sorted batch) + MLP head ----------------

__global__ __launch_bounds__(256) void pool_head_kernel(const float* __restrict__ h,
                                                        const int* __restrict__ batch,
                                                        const float* __restrict__ Wc1,
                                                        const float* __restrict__ bc1,
                                                        const float* __restrict__ Wc2,
                                                        const float* __restrict__ bc2,
                                                        float* __restrict__ out, int n) {
    __shared__ float pooled[160];
    __shared__ float z[80];
    __shared__ int range[2];
    int g = blockIdx.x;
    int t = threadIdx.x;
    if (t < 2) {
        int target = g + t;
        int lo = 0, hi = n;
        while (lo < hi) {
            int mid = (lo + hi) >> 1;
            if (batch[mid] < target) lo = mid + 1; else hi = mid;
        }
        range[t] = lo;
    }
    __syncthreads();
    int lo = range[0], hi = range[1];
    if (t < 160) {
        float s = 0.f;
        for (int r = lo; r < hi; ++r) s += h[(size_t)r * 160 + t];
        pooled[t] = s / fmaxf((float)(hi - lo), 1.f);
    }
    __syncthreads();
    if (t < 80) {
        float s = bc1[t];
        for (int k = 0; k < 160; ++k) s += pooled[k] * Wc1[k * 80 + t];
        z[t] = fmaxf(s, 0.f);
    }
    __syncthreads();
    if (t < 2) {
        float s = bc2[t];
        for (int k = 0; k < 80; ++k) s += z[k] * Wc2[k * 2 + t];
        out[g * 2 + t] = s;
    }
}

// ---------------- launch ----------------

static inline size_t align256(size_t x) { return (x + 255) & ~(size_t)255; }

extern "C" void kernel_launch(void* const* d_in, const int* in_sizes, int n_in,
                              void* d_out, int out_size, void* d_ws, size_t ws_size,
                              hipStream_t stream) {
    const float* x   = (const float*)d_in[0];
    const int* ei    = (const int*)d_in[1];
    const int* batch = (const int*)d_in[2];
    const float* W1  = (const float*)d_in[3];
    const float* b1  = (const float*)d_in[4];
    const float* W2  = (const float*)d_in[5];
    const float* b2  = (const float*)d_in[6];
    const float* W3  = (const float*)d_in[7];
    const float* b3  = (const float*)d_in[8];
    const float* g1  = (const float*)d_in[9];
    const float* be1 = (const float*)d_in[10];
    const float* m1  = (const float*)d_in[11];
    const float* v1  = (const float*)d_in[12];
    const float* g2  = (const float*)d_in[13];
    const float* be2 = (const float*)d_in[14];
    const float* m2  = (const float*)d_in[15];
    const float* v2  = (const float*)d_in[16];
    const float* g3  = (const float*)d_in[17];
    const float* be3 = (const float*)d_in[18];
    const float* m3  = (const float*)d_in[19];
    const float* v3  = (const float*)d_in[20];
    const float* Wc1 = (const float*)d_in[21];
    const float* bc1 = (const float*)d_in[22];
    const float* Wc2 = (const float*)d_in[23];
    const float* bc2 = (const float*)d_in[24];
    float* out = (float*)d_out;

    const int N = in_sizes[2];          // 50000
    const int E = in_sizes[1] / 2;      // 1600000
    const int* src = ei;
    const int* dst = ei + E;

    char* w = (char*)d_ws;
    int*   row_off = (int*)w;             w += align256((size_t)(N + 1) * 4);
    float* inv     = (float*)w;           w += align256((size_t)N * 4);
    int*   ssrc    = (int*)w;             w += align256((size_t)E * 4);
    unsigned int* pairs = (unsigned int*)w; w += align256((size_t)E * 4);
    int*   cg      = (int*)w;             w += align256((size_t)HIST_BLOCKS * NBKT_MAX * 4);
    int*   bucket_base   = (int*)w;       w += align256((size_t)(NBKT_MAX + 1) * 4);
    int*   bucket_cursor = (int*)w;       w += align256((size_t)NBKT_MAX * 4);
    float* scsh    = (float*)w;           w += align256((size_t)6 * HDIM * 4);
    unsigned short* W1p = (unsigned short*)w;  w += align256((size_t)FDIM_IN * HDIM * 2);
    unsigned short* W2p = (unsigned short*)w;  w += align256((size_t)HDIM * HDIM * 2);
    unsigned short* W3p = (unsigned short*)w;  w += align256((size_t)HDIM * HDIM * 2);
    unsigned short* bufA_bf = (unsigned short*)w;  w += align256((size_t)N * HDIM * 2);
    char* regionR = w;                    // reused region
    unsigned short* xs_bf = (unsigned short*)regionR;                           // N*128*2
    unsigned short* hs_bf = (unsigned short*)(regionR + align256((size_t)N * FDIM_IN * 2)); // N*160*2
    float* bufB = (float*)regionR;        // final h3 fp32 (aliases xs/hs, both dead by then)
    float* sc1 = scsh, *sh1 = scsh + 160, *sc2 = scsh + 320, *sh2 = scsh + 480,
         * sc3 = scsh + 640, *sh3 = scsh + 800;

    // two-level counting sort by dst -> row_off, ssrc, inv (+ fused x pre-scale)
    coarse_hist_kernel<<<HIST_BLOCKS, 256, 0, stream>>>(dst, cg, E);

    PrepArgs pa0 = {b1, g1, be1, m1, v1, sc1, sh1};
    PrepArgs pa1 = {b2, g2, be2, m2, v2, sc2, sh2};
    PrepArgs pa2 = {b3, g3, be3, m3, v3, sc3, sh3};
    int packTotal = 128 * 160 + 2 * 160 * 160;
    int setupBlocks = 4 + (packTotal + 255) / 256;
    setup_kernel<<<setupBlocks, 256, 0, stream>>>(cg, bucket_base, bucket_cursor,
                                                  pa0, pa1, pa2, W1, W2, W3, W1p, W2p, W3p);

    part_kernel<<<256, 256, 0, stream>>>(src, dst, bucket_cursor, pairs, E);
    int nbkt = (N + 511) >> 9;
    bucket_csr_kernel<<<nbkt, 1024, 0, stream>>>(pairs, bucket_base, row_off, inv, ssrc, x, xs_bf, N);

    int gAgg = (N + 3) / 4;
    int gGemm = (N + 63) / 64;

    // layer 1: agg; MFMA GEMM(K=128)+BN+ReLU -> bf16(h*inv)
    agg_grp_kernel<128><<<gAgg, 256, 0, stream>>>(xs_bf, inv, row_off, ssrc, bufA_bf, N);
    mfma_gemm_kernel<128, 1><<<gGemm, 256, 0, stream>>>(bufA_bf, W1p, sc1, sh1, inv, nullptr, hs_bf, N);
    // layer 2
    agg_grp_kernel<160><<<gAgg, 256, 0, stream>>>(hs_bf, inv, row_off, ssrc, bufA_bf, N);
    mfma_gemm_kernel<160, 1><<<gGemm, 256, 0, stream>>>(bufA_bf, W2p, sc2, sh2, inv, nullptr, hs_bf, N);
    // layer 3: fp32 unscaled h3 for pooling (bufB aliases dead xs/hs region)
    agg_grp_kernel<160><<<gAgg, 256, 0, stream>>>(hs_bf, inv, row_off, ssrc, bufA_bf, N);
    mfma_gemm_kernel<160, 0><<<gGemm, 256, 0, stream>>>(bufA_bf, W3p, sc3, sh3, inv, bufB, nullptr, N);

    pool_head_kernel<<<N_GRAPHS, 256, 0, stream>>>(bufB, batch, Wc1, bc1, Wc2, bc2, out, N);
}

// Round 8
// 459.286 us; speedup vs baseline: 1.1132x; 1.0156x over previous
//
#include <hip/hip_runtime.h>

#define N_NODES   50000
#define N_EDGES   1600000
#define FDIM_IN   128
#define HDIM      160
#define N_GRAPHS  512
#define BN_EPS    1e-5f
#define NBKT_MAX  256           // coarse buckets of 256 nodes (N<=65536)
#define BKT_SH    8             // log2(nodes per bucket)
#define HIST_BLOCKS 128         // kept at 128 rows so cg stays 128KB (R5 workspace footprint)

typedef short  frag8 __attribute__((ext_vector_type(8)));   // 8 x bf16
typedef float  facc4 __attribute__((ext_vector_type(4)));   // 4 x f32

// ---------------- bf16 helpers ----------------

__device__ __forceinline__ unsigned short f2bf(float f) {
    unsigned int u = __float_as_uint(f);
    return (unsigned short)((u + 0x7FFFu + ((u >> 16) & 1u)) >> 16);
}

__device__ __forceinline__ unsigned int pack2(float lo, float hi) {
    return (unsigned int)f2bf(lo) | ((unsigned int)f2bf(hi) << 16);
}

__device__ __forceinline__ void addpk(float* acc, uint4 r) {
    acc[0] += __uint_as_float(r.x << 16);
    acc[1] += __uint_as_float(r.x & 0xFFFF0000u);
    acc[2] += __uint_as_float(r.y << 16);
    acc[3] += __uint_as_float(r.y & 0xFFFF0000u);
    acc[4] += __uint_as_float(r.z << 16);
    acc[5] += __uint_as_float(r.z & 0xFFFF0000u);
    acc[6] += __uint_as_float(r.w << 16);
    acc[7] += __uint_as_float(r.w & 0xFFFF0000u);
}

// ---------------- two-level counting sort by dst ----------------
// per-block histogram rows cg[block][bucket] -> no memset, no global atomics.

__global__ __launch_bounds__(256) void coarse_hist_kernel(const int* __restrict__ dst,
                                                          int* __restrict__ cg, int E) {
    __shared__ int h[NBKT_MAX];
    int tid = threadIdx.x;
    if (tid < NBKT_MAX) h[tid] = 0;
    __syncthreads();
    for (int e = blockIdx.x * 256 + tid; e < E; e += gridDim.x * 256)
        atomicAdd(&h[dst[e] >> BKT_SH], 1);
    __syncthreads();
    if (tid < NBKT_MAX) cg[blockIdx.x * NBKT_MAX + tid] = h[tid];
}

// ---------------- merged setup: scan (block 0) + BN fold (blocks 1-3) + weight pack ----------------

struct PrepArgs {
    const float *b, *g, *be, *m, *v;
    float *sc, *sh;
};

__global__ __launch_bounds__(256) void setup_kernel(const int* __restrict__ cg,
                                                    int* __restrict__ bucket_base,
                                                    int* __restrict__ bucket_cursor,
                                                    PrepArgs a0, PrepArgs a1, PrepArgs a2,
                                                    const float* __restrict__ W1,
                                                    const float* __restrict__ W2,
                                                    const float* __restrict__ W3,
                                                    unsigned short* __restrict__ o1,
                                                    unsigned short* __restrict__ o2,
                                                    unsigned short* __restrict__ o3) {
    int bid = blockIdx.x;
    int t = threadIdx.x;
    if (bid == 0) {
        // column-sum the per-block histograms, then exclusive scan
        __shared__ int h[NBKT_MAX];
        __shared__ int total;
        if (t < NBKT_MAX) {
            int s = 0;
            for (int b = 0; b < HIST_BLOCKS; ++b) s += cg[b * NBKT_MAX + t];
            h[t] = s;
        }
        __syncthreads();
        if (t == 0) {
            int run = 0;
            for (int i = 0; i < NBKT_MAX; ++i) { int c = h[i]; h[i] = run; run += c; }
            total = run;
        }
        __syncthreads();
        if (t < NBKT_MAX) {
            bucket_base[t] = h[t];
            bucket_cursor[t] = h[t];
        }
        if (t == 0) bucket_base[NBKT_MAX] = total;
    } else if (bid <= 3) {
        PrepArgs a = (bid == 1) ? a0 : (bid == 2) ? a1 : a2;
        if (t < HDIM) {
            float s = a.g[t] * rsqrtf(a.v[t] + BN_EPS);
            a.sc[t] = s;
            a.sh[t] = (a.b[t] - a.m[t]) * s + a.be[t];
        }
    } else {
        int i = (bid - 4) * 256 + t;     // packed index over all three weights
        const float* W;
        unsigned short* o;
        if (i < 128 * 160)                 { W = W1; o = o1; }
        else if (i < 128 * 160 + 160 * 160) { W = W2; o = o2; i -= 128 * 160; }
        else if (i < 128 * 160 + 2 * 160 * 160) { W = W3; o = o3; i -= 128 * 160 + 160 * 160; }
        else return;
        int j = i & 7;
        int l = (i >> 3) & 63;
        int u = (i >> 9) % 10;
        int tt = i / 5120;
        int k = tt * 32 + (l >> 4) * 8 + j;
        int nn = u * 16 + (l & 15);
        o[i] = f2bf(W[k * 160 + nn]);
    }
}

// level 1: partition packed (src<<8 | dst&255) into coarse-bucket-contiguous regions
__global__ __launch_bounds__(256) void part_kernel(const int* __restrict__ src,
                                                   const int* __restrict__ dst,
                                                   int* __restrict__ bucket_cursor,
                                                   unsigned int* __restrict__ pairs, int E) {
    __shared__ int bcnt[NBKT_MAX], bbase[NBKT_MAX], lc[NBKT_MAX];
    int tid = threadIdx.x;
    int per = (E + gridDim.x - 1) / gridDim.x;
    int beg = blockIdx.x * per;
    int end = min(beg + per, E);
    if (tid < NBKT_MAX) { bcnt[tid] = 0; lc[tid] = 0; }
    __syncthreads();
    for (int e = beg + tid; e < end; e += 256)
        atomicAdd(&bcnt[dst[e] >> BKT_SH], 1);
    __syncthreads();
    if (tid < NBKT_MAX)
        bbase[tid] = bcnt[tid] ? atomicAdd(&bucket_cursor[tid], bcnt[tid]) : 0;
    __syncthreads();
    for (int e = beg + tid; e < end; e += 256) {
        int d = dst[e];
        int b = d >> BKT_SH;
        int pos = bbase[b] + atomicAdd(&lc[b], 1);
        pairs[pos] = ((unsigned int)src[e] << BKT_SH) | (unsigned int)(d & (NBKT_MAX - 1));
    }
}

// level 2: per-bucket exact CSR build + local scatter + fused x*inv bf16 pre-scale
__global__ __launch_bounds__(1024) void bucket_csr_kernel(const unsigned int* __restrict__ pairs,
                                                          const int* __restrict__ bucket_base,
                                                          int* __restrict__ row_off,
                                                          float* __restrict__ inv,
                                                          int* __restrict__ ssrc,
                                                          const float* __restrict__ x,
                                                          unsigned short* __restrict__ xs,
                                                          int n) {
    __shared__ int h[NBKT_MAX];
    __shared__ int ws[4];
    __shared__ float sinv[NBKT_MAX];
    int tid = threadIdx.x;
    int b = blockIdx.x;
    int node0 = b << BKT_SH;
    int beg = bucket_base[b], end = bucket_base[b + 1];
    if (tid < NBKT_MAX) h[tid] = 0;
    __syncthreads();
    for (int j = beg + tid; j < end; j += 1024)
        atomicAdd(&h[pairs[j] & (NBKT_MAX - 1)], 1);
    __syncthreads();
    int cntv = (tid < NBKT_MAX) ? h[tid] : 0;
    __syncthreads();
    int lane = tid & 63, wid = tid >> 6;
    int incl = cntv;
    #pragma unroll
    for (int off = 1; off < 64; off <<= 1) {
        int u = __shfl_up(incl, off);
        if (lane >= off) incl += u;
    }
    if (tid < NBKT_MAX && lane == 63) ws[wid] = incl;
    __syncthreads();
    if (tid == 0) {
        int r = 0;
        #pragma unroll
        for (int i = 0; i < 4; ++i) { int t = ws[i]; ws[i] = r; r += t; }
    }
    __syncthreads();
    int excl = (tid < NBKT_MAX) ? (ws[wid] + incl - cntv) : 0;
    if (tid < NBKT_MAX) {
        float iv = rsqrtf((float)(cntv + 1));    // +1 = self loop
        int node = node0 + tid;
        if (node < n) {
            row_off[node] = beg + excl;
            inv[node] = iv;
        }
        sinv[tid] = iv;
        h[tid] = excl;
    }
    if (tid == 0 && (node0 + NBKT_MAX) >= n) row_off[n] = end;
    __syncthreads();
    for (int j = beg + tid; j < end; j += 1024) {
        unsigned int p = pairs[j];
        int pos = beg + atomicAdd(&h[p & (NBKT_MAX - 1)], 1);
        ssrc[pos] = (int)(p >> BKT_SH);
    }
    // fused pre-scale: xs[node] = bf16(x[node] * inv[node]) for this bucket's nodes
    for (int idx = tid; idx < NBKT_MAX * 32; idx += 1024) {
        int nd = node0 + (idx >> 5);
        if (nd < n) {
            float w = sinv[idx >> 5];
            float4 v = ((const float4*)x)[(size_t)nd * 32 + (idx & 31)];
            ushort4 o;
            o.x = f2bf(v.x * w); o.y = f2bf(v.y * w);
            o.z = f2bf(v.z * w); o.w = f2bf(v.w * w);
            ((ushort4*)xs)[(size_t)nd * 32 + (idx & 31)] = o;
        }
    }
}

// ---------------- grouped-gather aggregation (bf16 in, bf16 out) ----------------
// Wave per node; wave split into G groups of LPR lanes; each group gathers a
// different edge's row with uint4 (16B) loads. C=160: G=3x20; C=128: G=4x16.
// 2-deep ladder (R1: deeper ILP neutral; R4: L2-residency neutral -> line-count path-bound).

template <int C>
__global__ __launch_bounds__(256) void agg_grp_kernel(const unsigned short* __restrict__ in_s,
                                                      const float* __restrict__ inv,
                                                      const int* __restrict__ row_off,
                                                      const int* __restrict__ ssrc,
                                                      unsigned short* __restrict__ out, int n) {
    constexpr int LPR = C / 8;          // lanes per row (uint4 = 8 ch)
    constexpr int G   = 64 / LPR;       // concurrent edges per wave
    constexpr int RB  = C * 2;          // row bytes
    int wave = threadIdx.x >> 6;
    int lane = threadIdx.x & 63;
    int node = blockIdx.x * 4 + wave;
    if (node >= n) return;
    int g  = lane / LPR;
    int cl = lane - g * LPR;
    bool act = g < G;
    int beg = row_off[node], end = row_off[node + 1];
    const char* base = (const char*)in_s;
    int lb = cl * 16;

    float acc[8];
    #pragma unroll
    for (int i = 0; i < 8; ++i) acc[i] = 0.f;

    if (g == 0) {   // self-loop term
        uint4 r = *(const uint4*)(base + (size_t)node * RB + lb);
        addpk(acc, r);
    }

    int e = act ? beg + g : end;
    for (; e + G < end; e += 2 * G) {
        int s0 = ssrc[e], s1 = ssrc[e + G];
        uint4 r0 = *(const uint4*)(base + (size_t)s0 * RB + lb);
        uint4 r1 = *(const uint4*)(base + (size_t)s1 * RB + lb);
        addpk(acc, r0);
        addpk(acc, r1);
    }
    if (e < end) {
        uint4 r = *(const uint4*)(base + (size_t)ssrc[e] * RB + lb);
        addpk(acc, r);
    }

    // cross-group combine
    if (G == 4) {
        #pragma unroll
        for (int i = 0; i < 8; ++i) acc[i] += __shfl(acc[i], lane + 32);
        #pragma unroll
        for (int i = 0; i < 8; ++i) acc[i] += __shfl(acc[i], lane + 16);
    } else {
        #pragma unroll
        for (int i = 0; i < 8; ++i) {
            float a = __shfl(acc[i], lane + 20);
            float b = __shfl(acc[i], lane + 40);
            acc[i] += a + b;
        }
    }

    if (lane < LPR) {
        float wi = inv[node];
        uint4 o;
        o.x = pack2(acc[0] * wi, acc[1] * wi);
        o.y = pack2(acc[2] * wi, acc[3] * wi);
        o.z = pack2(acc[4] * wi, acc[5] * wi);
        o.w = pack2(acc[6] * wi, acc[7] * wi);
        *(uint4*)((char*)out + (size_t)node * RB + lb) = o;
    }
}

// ---------------- MFMA GEMM v2: B panel staged in LDS, 128 rows/block ----------------
// relu((A[n x K]bf16 @ B[K x 160]bf16) * sc + sh); each wave owns 2 row-groups so
// every LDS B-fragment read feeds 2 MFMAs. B panel (40-51KB) no longer thrashes L1.

template <int K, int OUTMODE>
__global__ __launch_bounds__(256) void mfma_gemm_kernel(const unsigned short* __restrict__ A,
                                                        const unsigned short* __restrict__ Bp,
                                                        const float* __restrict__ sc,
                                                        const float* __restrict__ sh,
                                                        const float* __restrict__ inv,
                                                        float* __restrict__ CoutF,
                                                        unsigned short* __restrict__ CoutB,
                                                        int n) {
    constexpr int KT = K / 32;
    constexpr int BQ = K * 20;                   // uint4 count of packed B panel
    __shared__ uint4 Bs[BQ];
    int tid = threadIdx.x;
    for (int i = tid; i < BQ; i += 256) Bs[i] = ((const uint4*)Bp)[i];

    int wave = tid >> 6, lane = tid & 63;
    int m = lane & 15, q = lane >> 4;
    int row0 = blockIdx.x * 128 + wave * 16;     // row-group 0
    int row1 = row0 + 64;                        // row-group 1

    int ar0 = row0 + m; ar0 = (ar0 < n) ? ar0 : (n - 1);
    int ar1 = row1 + m; ar1 = (ar1 < n) ? ar1 : (n - 1);
    const frag8* A0 = (const frag8*)(A + (size_t)ar0 * K);   // frag idx = t*4 + q
    const frag8* A1 = (const frag8*)(A + (size_t)ar1 * K);
    const frag8* Bf = (const frag8*)Bs;                      // frag idx = (t*10+u)*64 + lane

    facc4 acc0[10], acc1[10];
    #pragma unroll
    for (int u = 0; u < 10; ++u) {
        acc0[u] = (facc4){0.f, 0.f, 0.f, 0.f};
        acc1[u] = (facc4){0.f, 0.f, 0.f, 0.f};
    }

    __syncthreads();

    #pragma unroll
    for (int t = 0; t < KT; ++t) {
        frag8 af0 = A0[t * 4 + q];
        frag8 af1 = A1[t * 4 + q];
        #pragma unroll
        for (int u = 0; u < 10; ++u) {
            frag8 bf = Bf[(t * 10 + u) * 64 + lane];
            acc0[u] = __builtin_amdgcn_mfma_f32_16x16x32_bf16(af0, bf, acc0[u], 0, 0, 0);
            acc1[u] = __builtin_amdgcn_mfma_f32_16x16x32_bf16(af1, bf, acc1[u], 0, 0, 0);
        }
    }

    // D layout: col = lane&15 (within tile), row = q*4 + reg
    #pragma unroll
    for (int u = 0; u < 10; ++u) {
        int c = u * 16 + m;
        float scv = sc[c], shv = sh[c];
        #pragma unroll
        for (int r = 0; r < 4; ++r) {
            int rr = row0 + q * 4 + r;
            if (rr < n) {
                float v = fmaxf(acc0[u][r] * scv + shv, 0.f);
                if (OUTMODE == 1) CoutB[(size_t)rr * 160 + c] = f2bf(v * inv[rr]);
                else              CoutF[(size_t)rr * 160 + c] = v;
            }
            int rr1 = row1 + q * 4 + r;
            if (rr1 < n) {
                float v = fmaxf(acc1[u][r] * scv + shv, 0.f);
                if (OUTMODE == 1) CoutB[(size_t)rr1 * 160 + c] = f2bf(v * inv[rr1]);
                else              CoutF[(size_t)rr1 * 160 + c] = v;
            }
        }
    }
}

// ---------------- mean pool (sorted batch) + MLP head ----------------
// float4 row loads, 6 rows in flight per block (240/256 lanes active), LDS reduce.

__global__ __launch_bounds__(256) void pool_head_kernel(const float* __restrict__ h,
                                                        const int* __restrict__ batch,
                                                        const float* __restrict__ Wc1,
                                                        const float* __restrict__ bc1,
                                                        const float* __restrict__ Wc2,
                                                        const float* __restrict__ bc2,
                                                        float* __restrict__ out, int n) {
    __shared__ float4 part[6][40];
    __shared__ float pooled[160];
    __shared__ float z[80];
    __shared__ int range[2];
    int g = blockIdx.x;
    int t = threadIdx.x;
    if (t < 2) {
        int target = g + t;
        int lo = 0, hi = n;
        while (lo < hi) {
            int mid = (lo + hi) >> 1;
            if (batch[mid] < target) lo = mid + 1; else hi = mid;
        }
        range[t] = lo;
    }
    __syncthreads();
    int lo = range[0], hi = range[1];
    int sub = t / 40, c4 = t - sub * 40;
    if (sub < 6) {
        float4 a = {0.f, 0.f, 0.f, 0.f};
        for (int r = lo + sub; r < hi; r += 6) {
            float4 v = ((const float4*)(h + (size_t)r * 160))[c4];
            a.x += v.x; a.y += v.y; a.z += v.z; a.w += v.w;
        }
        part[sub][c4] = a;
    }
    __syncthreads();
    if (t < 40) {
        float4 s = {0.f, 0.f, 0.f, 0.f};
        #pragma unroll
        for (int i = 0; i < 6; ++i) {
            float4 p = part[i][t];
            s.x += p.x; s.y += p.y; s.z += p.z; s.w += p.w;
        }
        float ic = 1.f / fmaxf((float)(hi - lo), 1.f);
        pooled[t * 4 + 0] = s.x * ic;
        pooled[t * 4 + 1] = s.y * ic;
        pooled[t * 4 + 2] = s.z * ic;
        pooled[t * 4 + 3] = s.w * ic;
    }
    __syncthreads();
    if (t < 80) {
        float s = bc1[t];
        for (int k = 0; k < 160; ++k) s += pooled[k] * Wc1[k * 80 + t];
        z[t] = fmaxf(s, 0.f);
    }
    __syncthreads();
    if (t < 2) {
        float s = bc2[t];
        for (int k = 0; k < 80; ++k) s += z[k] * Wc2[k * 2 + t];
        out[g * 2 + t] = s;
    }
}

// ---------------- launch ----------------

static inline size_t align256(size_t x) { return (x + 255) & ~(size_t)255; }

extern "C" void kernel_launch(void* const* d_in, const int* in_sizes, int n_in,
                              void* d_out, int out_size, void* d_ws, size_t ws_size,
                              hipStream_t stream) {
    const float* x   = (const float*)d_in[0];
    const int* ei    = (const int*)d_in[1];
    const int* batch = (const int*)d_in[2];
    const float* W1  = (const float*)d_in[3];
    const float* b1  = (const float*)d_in[4];
    const float* W2  = (const float*)d_in[5];
    const float* b2  = (const float*)d_in[6];
    const float* W3  = (const float*)d_in[7];
    const float* b3  = (const float*)d_in[8];
    const float* g1  = (const float*)d_in[9];
    const float* be1 = (const float*)d_in[10];
    const float* m1  = (const float*)d_in[11];
    const float* v1  = (const float*)d_in[12];
    const float* g2  = (const float*)d_in[13];
    const float* be2 = (const float*)d_in[14];
    const float* m2  = (const float*)d_in[15];
    const float* v2  = (const float*)d_in[16];
    const float* g3  = (const float*)d_in[17];
    const float* be3 = (const float*)d_in[18];
    const float* m3  = (const float*)d_in[19];
    const float* v3  = (const float*)d_in[20];
    const float* Wc1 = (const float*)d_in[21];
    const float* bc1 = (const float*)d_in[22];
    const float* Wc2 = (const float*)d_in[23];
    const float* bc2 = (const float*)d_in[24];
    float* out = (float*)d_out;

    const int N = in_sizes[2];          // 50000
    const int E = in_sizes[1] / 2;      // 1600000
    const int* src = ei;
    const int* dst = ei + E;

    char* w = (char*)d_ws;
    int*   row_off = (int*)w;             w += align256((size_t)(N + 1) * 4);
    float* inv     = (float*)w;           w += align256((size_t)N * 4);
    int*   ssrc    = (int*)w;             w += align256((size_t)E * 4);
    unsigned int* pairs = (unsigned int*)w; w += align256((size_t)E * 4);
    int*   cg      = (int*)w;             w += align256((size_t)HIST_BLOCKS * NBKT_MAX * 4);
    int*   bucket_base   = (int*)w;       w += align256((size_t)(NBKT_MAX + 1) * 4);
    int*   bucket_cursor = (int*)w;       w += align256((size_t)NBKT_MAX * 4);
    float* scsh    = (float*)w;           w += align256((size_t)6 * HDIM * 4);
    unsigned short* W1p = (unsigned short*)w;  w += align256((size_t)FDIM_IN * HDIM * 2);
    unsigned short* W2p = (unsigned short*)w;  w += align256((size_t)HDIM * HDIM * 2);
    unsigned short* W3p = (unsigned short*)w;  w += align256((size_t)HDIM * HDIM * 2);
    unsigned short* bufA_bf = (unsigned short*)w;  w += align256((size_t)N * HDIM * 2);
    char* regionR = w;                    // reused region
    unsigned short* xs_bf = (unsigned short*)regionR;                           // N*128*2
    unsigned short* hs_bf = (unsigned short*)(regionR + align256((size_t)N * FDIM_IN * 2)); // N*160*2
    float* bufB = (float*)regionR;        // final h3 fp32 (aliases xs/hs, both dead by then)
    float* sc1 = scsh, *sh1 = scsh + 160, *sc2 = scsh + 320, *sh2 = scsh + 480,
         * sc3 = scsh + 640, *sh3 = scsh + 800;

    // two-level counting sort by dst -> row_off, ssrc, inv (+ fused x pre-scale)
    coarse_hist_kernel<<<HIST_BLOCKS, 256, 0, stream>>>(dst, cg, E);

    PrepArgs pa0 = {b1, g1, be1, m1, v1, sc1, sh1};
    PrepArgs pa1 = {b2, g2, be2, m2, v2, sc2, sh2};
    PrepArgs pa2 = {b3, g3, be3, m3, v3, sc3, sh3};
    int packTotal = 128 * 160 + 2 * 160 * 160;
    int setupBlocks = 4 + (packTotal + 255) / 256;
    setup_kernel<<<setupBlocks, 256, 0, stream>>>(cg, bucket_base, bucket_cursor,
                                                  pa0, pa1, pa2, W1, W2, W3, W1p, W2p, W3p);

    part_kernel<<<256, 256, 0, stream>>>(src, dst, bucket_cursor, pairs, E);
    int nbkt = (N + NBKT_MAX - 1) >> BKT_SH;
    bucket_csr_kernel<<<nbkt, 1024, 0, stream>>>(pairs, bucket_base, row_off, inv, ssrc, x, xs_bf, N);

    int gAgg = (N + 3) / 4;
    int gGemm = (N + 127) / 128;

    // layer 1: agg; MFMA GEMM(K=128)+BN+ReLU -> bf16(h*inv)
    agg_grp_kernel<128><<<gAgg, 256, 0, stream>>>(xs_bf, inv, row_off, ssrc, bufA_bf, N);
    mfma_gemm_kernel<128, 1><<<gGemm, 256, 0, stream>>>(bufA_bf, W1p, sc1, sh1, inv, nullptr, hs_bf, N);
    // layer 2
    agg_grp_kernel<160><<<gAgg, 256, 0, stream>>>(hs_bf, inv, row_off, ssrc, bufA_bf, N);
    mfma_gemm_kernel<160, 1><<<gGemm, 256, 0, stream>>>(bufA_bf, W2p, sc2, sh2, inv, nullptr, hs_bf, N);
    // layer 3: fp32 unscaled h3 for pooling (bufB aliases dead xs/hs region)
    agg_grp_kernel<160><<<gAgg, 256, 0, stream>>>(hs_bf, inv, row_off, ssrc, bufA_bf, N);
    mfma_gemm_kernel<160, 0><<<gGemm, 256, 0, stream>>>(bufA_bf, W3p, sc3, sh3, inv, bufB, nullptr, N);

    pool_head_kernel<<<N_GRAPHS, 256, 0, stream>>>(bufB, batch, Wc1, bc1, Wc2, bc2, out, N);
}